// Round 12
// baseline (65.187 us; speedup 1.0000x reference)
//
#include <hip/hip_runtime.h>
#include <hip/hip_bf16.h>

// FilterBank via bf16 MFMA, swapped operands:
//   D[t_row, band_col] = sum_k A[t,k] B[k,band],  A[i,k] = xpad[t0+i+k+2],
//   B[k,n] = W[n,k]  (xpad[i] = x[i-64], zero outside [0,1000))
// C/D layout: col = lane&15 = band n, row = 4*(lane>>4)+reg = t -> lane's 4
// acc regs are 4 CONSECUTIVE t of one band.
// Round 12: NO x-LDS staging. Each lane loads its A-window x[xi0..xi0+7]
// DIRECTLY from global as two align-4 float4 (dense ~190B/wave-instr
// footprint, L1-resident row slice) and converts to bf16 in registers.
// Kills the 40-scattered-load prologue, the block barrier, and all
// ds_read_b128 traffic that every 52-62us variant shared. Boundary windows
// (wave-uniform test) use guarded scalar loads. Taps via small LDS tile
// (r11). Persistent 16-chain compute, direct stores, XCD swizzle.

#define T_LEN     1000
#define NB        9
#define WT_STRIDE 136      // shorts per tap row (272B stride: 2-way = free)

typedef __attribute__((ext_vector_type(8))) short short8;
typedef __attribute__((ext_vector_type(4))) float f32x4;
typedef float f32x4a __attribute__((ext_vector_type(4), aligned(4)));

__device__ __forceinline__ unsigned int f2bf(float f) {
    union { __hip_bfloat16 h; unsigned short u; } cv;
    cv.h = __float2bfloat16(f);
    return (unsigned int)cv.u;
}

__device__ __forceinline__ short8 load_win(const float* __restrict__ xrow,
                                           int xi0, bool safe) {
    float v[8];
    if (safe) {
        f32x4a a = *reinterpret_cast<const f32x4a*>(xrow + xi0);
        f32x4a b = *reinterpret_cast<const f32x4a*>(xrow + xi0 + 4);
        v[0] = a.x; v[1] = a.y; v[2] = a.z; v[3] = a.w;
        v[4] = b.x; v[5] = b.y; v[6] = b.z; v[7] = b.w;
    } else {
        #pragma unroll
        for (int e = 0; e < 8; ++e) {
            int xi = xi0 + e;
            v[e] = ((unsigned)xi < T_LEN) ? xrow[xi] : 0.f;
        }
    }
    union { uint4 u4; short8 s8; } cv;
    cv.u4 = make_uint4(f2bf(v[0]) | (f2bf(v[1]) << 16),
                       f2bf(v[2]) | (f2bf(v[3]) << 16),
                       f2bf(v[4]) | (f2bf(v[5]) << 16),
                       f2bf(v[6]) | (f2bf(v[7]) << 16));
    return cv.s8;
}

__global__ __launch_bounds__(256) void fbank_mfma(
    const float* __restrict__ x,
    const float* __restrict__ kern,
    float* __restrict__ out)
{
    __shared__ unsigned short wt[16 * WT_STRIDE];   // 4352 B (taps only)

    const int tid = threadIdx.x;
    const int bid = blockIdx.x;
    // XCD swizzle: contiguous 512-row chunk per XCD (4096 % 8 == 0, bijective)
    const int bc  = ((bid & 7) << 9) + (bid >> 3);
    const int b   = bc >> 6, c = bc & 63;
    const float* xrow = x + (size_t)bc * T_LEN;

    // ---- stage taps into LDS: thread t -> [band = t>>4][k = (t&15)*8 .. +7] ----
    {
        const int band = tid >> 4, k0 = (tid & 15) << 3;
        unsigned int d[4];
        #pragma unroll
        for (int e2 = 0; e2 < 4; ++e2) {
            int k = k0 + 2 * e2;
            float v0 = (band < NB && k < 125)     ? kern[band * 125 + k]     : 0.f;
            float v1 = (band < NB && k + 1 < 125) ? kern[band * 125 + k + 1] : 0.f;
            d[e2] = f2bf(v0) | (f2bf(v1) << 16);
        }
        *reinterpret_cast<uint4*>(&wt[band * WT_STRIDE + k0]) =
            make_uint4(d[0], d[1], d[2], d[3]);
    }

    const int lane = tid & 63;
    const int wid  = tid >> 6;
    const int n = lane & 15, g = lane >> 4;      // n = band col, g = k/row group

    __syncthreads();

    // ---- B frags (taps) from LDS ----
    short8 bt[4];
    #pragma unroll
    for (int kk = 0; kk < 4; ++kk)
        bt[kk] = *reinterpret_cast<const short8*>(wt + n * WT_STRIDE + kk * 32 + g * 8);

    const int t0w = wid << 8;                    // wave owns t in [256w, 256w+256)
    // A window u covers xpad[s0+16u .. +7], s0 = t0w+2+n+8g; x idx = s - 64
    const int xi_base = t0w + 2 + n + 8 * g - 64;

    short8 F[8];
    #pragma unroll
    for (int u = 0; u < 6; ++u) {
        const bool safe = (t0w + 16 * u >= 62) && (t0w + 16 * u <= 1015);
        F[u] = load_win(xrow, xi_base + 16 * u, safe);
    }

    // ---- compute: 16 persistent acc chains ----
    f32x4 acc[16];
    #pragma unroll
    for (int m = 0; m < 16; ++m) {
        const int u = m + 6;
        const bool safe = (t0w + 16 * u >= 62) && (t0w + 16 * u <= 1015);
        F[u & 7] = load_win(xrow, xi_base + 16 * u, safe);
        f32x4 a = {0.f, 0.f, 0.f, 0.f};
        #pragma unroll
        for (int kk = 0; kk < 4; ++kk)
            a = __builtin_amdgcn_mfma_f32_16x16x32_bf16(F[(m + 2 * kk) & 7], bt[kk], a, 0, 0, 0);
        acc[m] = a;
    }

    // ---- direct stores ----
    const bool bandok = (n < NB);
    float* obase = out + ((size_t)(b * NB + n) * 64 + c) * T_LEN + t0w + 4 * g;
    #pragma unroll
    for (int m = 0; m < 16; ++m) {
        const int t4 = t0w + 16 * m + 4 * g;
        if (bandok && t4 + 4 <= T_LEN)
            *reinterpret_cast<f32x4*>(obase + 16 * m) = acc[m];
    }
}

extern "C" void kernel_launch(void* const* d_in, const int* in_sizes, int n_in,
                              void* d_out, int out_size, void* d_ws, size_t ws_size,
                              hipStream_t stream) {
    const float* x    = (const float*)d_in[0];
    const float* kern = (const float*)d_in[1];
    float* out = (float*)d_out;

    fbank_mfma<<<64 * 64, 256, 0, stream>>>(x, kern, out);
}